// Round 5
// baseline (396.553 us; speedup 1.0000x reference)
//
#include <hip/hip_runtime.h>
#include <math.h>

#define NNODES 38400
#define KNBR 8
#define BK 32

typedef __attribute__((ext_vector_type(8))) short bf16x8;
typedef __attribute__((ext_vector_type(4))) short short4v;
typedef __attribute__((ext_vector_type(4))) float f32x4;

// Round-to-nearest-even split of fp32 into hi+lo bf16 (bit patterns).
static __device__ inline void split_bf16(float x, short& hi, short& lo) {
    unsigned u = __float_as_uint(x);
    unsigned r = (u + 0x7FFFu + ((u >> 16) & 1u)) & 0xFFFF0000u;
    hi = (short)(r >> 16);
    float rem = x - __uint_as_float(r);
    unsigned u2 = __float_as_uint(rem);
    unsigned r2 = (u2 + 0x7FFFu + ((u2 >> 16) & 1u));
    lo = (short)(r2 >> 16);
}

// Swizzled LDS element offset: row r (0..127) of 32 bf16, 16B chunk c (0..3),
// rotated by (r>>1)&3 -> ds_read_b128 across 16 rows is <=2-way (free).
static __device__ inline int lds_off(int r, int c) {
    return r * 32 + (((c + (r >> 1)) & 3) << 3);
}

// ---- MFMA GEMM on pre-split bf16 planes ----------------------------------
// Y[M, 2D] = A[M,K] @ [Wt; Wp]^T, A/W given as hi/lo bf16 planes (K padded
// to Kp, zeros in pad). 128x128 tile, BK=32, 4 waves (2x2), 64x64/wave.
// MFMA operands swapped -> transposed fragments -> float4 C stores.
__global__ __launch_bounds__(256) void gemm_planes(
    const short* __restrict__ Ahi, const short* __restrict__ Alo, int Kp, int nk,
    const short* __restrict__ Bthi, const short* __restrict__ Btlo,
    const short* __restrict__ Bphi, const short* __restrict__ Bplo,
    int D, float* __restrict__ Y)
{
    const int ldY = 2 * D;
    const int row0 = blockIdx.x * 128;
    const int col0 = blockIdx.y * 128;
    const int tid = threadIdx.x;
    const int lane = tid & 63, wid = tid >> 6;
    const int wm = wid >> 1, wn = wid & 1;

    __shared__ short Ah_s[128 * 32];
    __shared__ short Al_s[128 * 32];
    __shared__ short Bh_s[128 * 32];
    __shared__ short Bl_s[128 * 32];

    const int lr = tid >> 1;          // staging row (tile row / tile col)
    const int hc = (tid & 1) * 2;     // first of two 16B chunks

    // A source (rows always in range: M is a multiple of 128)
    const short* a_hi_src = Ahi + (size_t)(row0 + lr) * Kp + hc * 8;
    const short* a_lo_src = Alo + (size_t)(row0 + lr) * Kp + hc * 8;
    // B source: tile col -> theta row / phi row / zero
    const int bcol = col0 + lr;
    const short* b_hi_src = nullptr;
    const short* b_lo_src = nullptr;
    if (bcol < D) {
        b_hi_src = Bthi + (size_t)bcol * Kp + hc * 8;
        b_lo_src = Btlo + (size_t)bcol * Kp + hc * 8;
    } else if (bcol < 2 * D) {
        b_hi_src = Bphi + (size_t)(bcol - D) * Kp + hc * 8;
        b_lo_src = Bplo + (size_t)(bcol - D) * Kp + hc * 8;
    }

    bf16x8 rAh[2], rAl[2], rBh[2], rBl[2];

    auto load_tile = [&](int ks) {
        const int ko = ks * BK;
        rAh[0] = *(const bf16x8*)(a_hi_src + ko);
        rAh[1] = *(const bf16x8*)(a_hi_src + ko + 8);
        rAl[0] = *(const bf16x8*)(a_lo_src + ko);
        rAl[1] = *(const bf16x8*)(a_lo_src + ko + 8);
        if (b_hi_src) {
            rBh[0] = *(const bf16x8*)(b_hi_src + ko);
            rBh[1] = *(const bf16x8*)(b_hi_src + ko + 8);
            rBl[0] = *(const bf16x8*)(b_lo_src + ko);
            rBl[1] = *(const bf16x8*)(b_lo_src + ko + 8);
        } else {
            bf16x8 z = {};
            rBh[0] = z; rBh[1] = z; rBl[0] = z; rBl[1] = z;
        }
    };

    f32x4 acc[4][4] = {};
    load_tile(0);

    for (int ks = 0; ks < nk; ++ks) {
        __syncthreads();   // previous iteration's LDS reads complete
        *(bf16x8*)&Ah_s[lds_off(lr, hc)]     = rAh[0];
        *(bf16x8*)&Ah_s[lds_off(lr, hc + 1)] = rAh[1];
        *(bf16x8*)&Al_s[lds_off(lr, hc)]     = rAl[0];
        *(bf16x8*)&Al_s[lds_off(lr, hc + 1)] = rAl[1];
        *(bf16x8*)&Bh_s[lds_off(lr, hc)]     = rBh[0];
        *(bf16x8*)&Bh_s[lds_off(lr, hc + 1)] = rBh[1];
        *(bf16x8*)&Bl_s[lds_off(lr, hc)]     = rBl[0];
        *(bf16x8*)&Bl_s[lds_off(lr, hc + 1)] = rBl[1];
        __syncthreads();
        if (ks + 1 < nk) load_tile(ks + 1);   // overlap next loads with MFMA

        const int fr = lane & 15, g = lane >> 4;
        bf16x8 bh[4], bl[4];
#pragma unroll
        for (int f = 0; f < 4; ++f) {
            int bc = wn * 64 + f * 16 + fr;
            bh[f] = *(const bf16x8*)&Bh_s[lds_off(bc, g)];
            bl[f] = *(const bf16x8*)&Bl_s[lds_off(bc, g)];
        }
#pragma unroll
        for (int fm = 0; fm < 4; ++fm) {
            int ar = wm * 64 + fm * 16 + fr;
            bf16x8 ah = *(const bf16x8*)&Ah_s[lds_off(ar, g)];
            bf16x8 al = *(const bf16x8*)&Al_s[lds_off(ar, g)];
#pragma unroll
            for (int fn = 0; fn < 4; ++fn) {
                // swapped operands: D' fragments are C^T
                acc[fm][fn] = __builtin_amdgcn_mfma_f32_16x16x32_bf16(
                    bh[fn], ah, acc[fm][fn], 0, 0, 0);
                acc[fm][fn] = __builtin_amdgcn_mfma_f32_16x16x32_bf16(
                    bl[fn], ah, acc[fm][fn], 0, 0, 0);
                acc[fm][fn] = __builtin_amdgcn_mfma_f32_16x16x32_bf16(
                    bh[fn], al, acc[fm][fn], 0, 0, 0);
            }
        }
    }

    // store: lane&15 = our row, (lane>>4)*4+reg = our col (4 consecutive)
#pragma unroll
    for (int fm = 0; fm < 4; ++fm) {
        int row = row0 + wm * 64 + fm * 16 + (lane & 15);
#pragma unroll
        for (int fn = 0; fn < 4; ++fn) {
            int col = col0 + wn * 64 + fn * 16 + (lane >> 4) * 4;
            if (col < ldY) {
                __builtin_nontemporal_store(
                    acc[fm][fn], (f32x4*)(Y + (size_t)row * ldY + col));
            }
        }
    }
}

// ---- split X (fp32 [N][50] -> hi/lo bf16 planes [N][64], zero-padded) ----
__global__ __launch_bounds__(256) void split_x(
    const float* __restrict__ X, short* __restrict__ Hhi, short* __restrict__ Hlo)
{
    const int total = NNODES * 16;   // Kp=64 -> 16 chunks of 4
    for (int idx = blockIdx.x * 256 + threadIdx.x; idx < total;
         idx += gridDim.x * 256) {
        int n = idx >> 4, c = (idx & 15) << 2;
        short4v hi, lo;
#pragma unroll
        for (int j = 0; j < 4; ++j) {
            int e = c + j;
            float v = (e < 50) ? X[(size_t)n * 50 + e] : 0.f;
            short h, l; split_bf16(v, h, l);
            hi[j] = h; lo[j] = l;
        }
        *(short4v*)&Hhi[(size_t)n * 64 + c] = hi;
        *(short4v*)&Hlo[(size_t)n * 64 + c] = lo;
    }
}

// ---- split all weight matrices into hi/lo planes -------------------------
struct WSplitArgs {
    const float* w[6]; short* hi[6]; short* lo[6];
    int rows[6], ci[6], kp[6], chunks[6];
    int total;
};
__global__ __launch_bounds__(256) void split_w(WSplitArgs a)
{
    for (int idx = blockIdx.x * 256 + threadIdx.x; idx < a.total;
         idx += gridDim.x * 256) {
        int seg = 0, rem = idx;
        while (rem >= a.chunks[seg]) { rem -= a.chunks[seg]; ++seg; }
        const int kp4 = a.kp[seg] >> 2;
        const int row = rem / kp4;
        const int c = (rem - row * kp4) << 2;
        const int ci = a.ci[seg];
        const float* w = a.w[seg] + (size_t)row * ci;
        short4v hi, lo;
#pragma unroll
        for (int j = 0; j < 4; ++j) {
            int e = c + j;
            float v = (e < ci) ? w[e] : 0.f;
            short h, l; split_bf16(v, h, l);
            hi[j] = h; lo[j] = l;
        }
        size_t o = (size_t)row * a.kp[seg] + c;
        *(short4v*)&a.hi[seg][o] = hi;
        *(short4v*)&a.lo[seg][o] = lo;
    }
}

// ---- EdgeConv epilogue (layers 1-2): tanh + emit hi/lo planes ------------
// kp MUST equal 4 << kp4shift (chunk count is a power of two).
__global__ __launch_bounds__(256) void epi_flat(
    const float* __restrict__ Y, int Co, int kp, int kp4shift,
    const int* __restrict__ nbr,
    const float* __restrict__ tb, const float* __restrict__ pb,
    short* __restrict__ Hhi, short* __restrict__ Hlo)
{
    const int ld = 2 * Co;
    const int total = NNODES << kp4shift;
    for (int idx = blockIdx.x * 256 + threadIdx.x; idx < total;
         idx += gridDim.x * 256) {
        const int n = idx >> kp4shift;
        const int c = (idx & ((1 << kp4shift) - 1)) << 2;
        if (c >= Co) {   // zero pad region
            short4v z = {};
            *(short4v*)&Hhi[(size_t)n * kp + c] = z;
            *(short4v*)&Hlo[(size_t)n * kp + c] = z;
            continue;
        }
        const int* jn = nbr + n * KNBR;
        float4 m = make_float4(-INFINITY, -INFINITY, -INFINITY, -INFINITY);
#pragma unroll
        for (int k = 0; k < KNBR; ++k) {
            float4 v = *(const float4*)(Y + (size_t)jn[k] * ld + c);
            m.x = fmaxf(m.x, v.x); m.y = fmaxf(m.y, v.y);
            m.z = fmaxf(m.z, v.z); m.w = fmaxf(m.w, v.w);
        }
        float4 yt = *(const float4*)(Y + (size_t)n * ld + c);
        float4 yp = *(const float4*)(Y + (size_t)n * ld + Co + c);
        float4 b1 = *(const float4*)(tb + c);
        float4 b2 = *(const float4*)(pb + c);
        float o0 = tanhf(m.x - yt.x + b1.x + yp.x + b2.x);
        float o1 = tanhf(m.y - yt.y + b1.y + yp.y + b2.y);
        float o2 = tanhf(m.z - yt.z + b1.z + yp.z + b2.z);
        float o3 = tanhf(m.w - yt.w + b1.w + yp.w + b2.w);
        short4v hi, lo;
        short h, l;
        split_bf16(o0, h, l); hi[0] = h; lo[0] = l;
        split_bf16(o1, h, l); hi[1] = h; lo[1] = l;
        split_bf16(o2, h, l); hi[2] = h; lo[2] = l;
        split_bf16(o3, h, l); hi[3] = h; lo[3] = l;
        *(short4v*)&Hhi[(size_t)n * kp + c] = hi;
        *(short4v*)&Hlo[(size_t)n * kp + c] = lo;
    }
}

// ---- Layer-3 epilogue: one wave per node, channel-max into g[n] ----------
__global__ __launch_bounds__(256) void epi3_wave(
    const float* __restrict__ Y, int D,
    const int* __restrict__ nbr,
    const float* __restrict__ tb, const float* __restrict__ pb,
    float* __restrict__ g, int first)
{
    const int node = blockIdx.x * 4 + (threadIdx.x >> 6);
    if (node >= NNODES) return;
    const int lane = threadIdx.x & 63;
    const int ld = 2 * D;
    const int* jn = nbr + node * KNBR;
    int j[KNBR];
#pragma unroll
    for (int k = 0; k < KNBR; ++k) j[k] = jn[k];
    float mx = -INFINITY;
    for (int c4 = lane; c4 < (D >> 2); c4 += 64) {
        const int c = c4 << 2;
        float4 m = make_float4(-INFINITY, -INFINITY, -INFINITY, -INFINITY);
#pragma unroll
        for (int k = 0; k < KNBR; ++k) {
            float4 v = *(const float4*)(Y + (size_t)j[k] * ld + c);
            m.x = fmaxf(m.x, v.x); m.y = fmaxf(m.y, v.y);
            m.z = fmaxf(m.z, v.z); m.w = fmaxf(m.w, v.w);
        }
        float4 yt = *(const float4*)(Y + (size_t)node * ld + c);
        float4 yp = *(const float4*)(Y + (size_t)node * ld + D + c);
        float4 b1 = *(const float4*)(tb + c);
        float4 b2 = *(const float4*)(pb + c);
        mx = fmaxf(mx, m.x - yt.x + b1.x + yp.x + b2.x);
        mx = fmaxf(mx, m.y - yt.y + b1.y + yp.y + b2.y);
        mx = fmaxf(mx, m.z - yt.z + b1.z + yp.z + b2.z);
        mx = fmaxf(mx, m.w - yt.w + b1.w + yp.w + b2.w);
    }
#pragma unroll
    for (int off = 1; off < 64; off <<= 1)
        mx = fmaxf(mx, __shfl_xor(mx, off));
    if (lane == 0) g[node] = first ? mx : fmaxf(g[node], mx);
}

// ---------------- FC head: one block per graph ----------------------------
__global__ __launch_bounds__(256) void fc_head(
    const float* __restrict__ g,
    const float* __restrict__ fc1w, const float* __restrict__ fc1b,
    const float* __restrict__ fc2w, const float* __restrict__ fc2b,
    const float* __restrict__ fc3w, const float* __restrict__ fc3b,
    const float* __restrict__ fc4w, const float* __restrict__ fc4b,
    const float* __restrict__ fow,  const float* __restrict__ fob,
    float* __restrict__ out)
{
    __shared__ float a[600];
    __shared__ float b[300];
    const int bidx = blockIdx.x;
    const int t = threadIdx.x;
    for (int i = t; i < 600; i += 256) a[i] = g[bidx * 600 + i];
    __syncthreads();
    for (int o = t; o < 300; o += 256) {
        float s = fc1b[o];
        for (int c = 0; c < 600; ++c) s += a[c] * fc1w[o * 600 + c];
        b[o] = tanhf(s);
    }
    __syncthreads();
    for (int o = t; o < 300; o += 256) {
        float s = fc2b[o];
        for (int c = 0; c < 300; ++c) s += b[c] * fc2w[o * 300 + c];
        a[o] = tanhf(s);
    }
    __syncthreads();
    for (int o = t; o < 100; o += 256) {
        float s = fc3b[o];
        for (int c = 0; c < 300; ++c) s += a[c] * fc3w[o * 300 + c];
        b[o] = tanhf(s);
    }
    __syncthreads();
    for (int o = t; o < 50; o += 256) {
        float s = fc4b[o];
        for (int c = 0; c < 100; ++c) s += b[c] * fc4w[o * 100 + c];
        a[o] = tanhf(s);
    }
    __syncthreads();
    for (int o = t; o < 9; o += 256) {
        float s = fob[o];
        for (int c = 0; c < 50; ++c) s += a[c] * fow[o * 50 + c];
        out[bidx * 9 + o] = fminf(fmaxf(s, -2.f), 2.f);
    }
}

extern "C" void kernel_launch(void* const* d_in, const int* in_sizes, int n_in,
                              void* d_out, int out_size, void* d_ws, size_t ws_size,
                              hipStream_t stream)
{
    const float* inputs = (const float*)d_in[0];
    const int*   nbr    = (const int*)d_in[1];
    const float* t1w = (const float*)d_in[2];  const float* t1b = (const float*)d_in[3];
    const float* p1w = (const float*)d_in[4];  const float* p1b = (const float*)d_in[5];
    const float* t2w = (const float*)d_in[6];  const float* t2b = (const float*)d_in[7];
    const float* p2w = (const float*)d_in[8];  const float* p2b = (const float*)d_in[9];
    const float* t3w = (const float*)d_in[10]; const float* t3b = (const float*)d_in[11];
    const float* p3w = (const float*)d_in[12]; const float* p3b = (const float*)d_in[13];
    const float* fc1w = (const float*)d_in[14]; const float* fc1b = (const float*)d_in[15];
    const float* fc2w = (const float*)d_in[16]; const float* fc2b = (const float*)d_in[17];
    const float* fc3w = (const float*)d_in[18]; const float* fc3b = (const float*)d_in[19];
    const float* fc4w = (const float*)d_in[20]; const float* fc4b = (const float*)d_in[21];
    const float* fow  = (const float*)d_in[22]; const float* fob  = (const float*)d_in[23];
    float* out = (float*)d_out;

    const int N = NNODES;
    // Kp3 = 256 (not 224): epi_flat's power-of-two chunk indexing must match
    // the padded row length exactly, else pad writes spill into the next row.
    const int Kp1 = 64, Kp2 = 128, Kp3 = 256;

    char* ws = (char*)d_ws;
    size_t off = 0;
    auto alloc = [&](size_t bytes) {
        void* p = ws + off;
        off = (off + bytes + 255) & ~(size_t)255;
        return p;
    };
    short* Xhi = (short*)alloc((size_t)N * Kp1 * 2);
    short* Xlo = (short*)alloc((size_t)N * Kp1 * 2);
    short* H1hi = (short*)alloc((size_t)N * Kp2 * 2);
    short* H1lo = (short*)alloc((size_t)N * Kp2 * 2);
    short* H2hi = (short*)alloc((size_t)N * Kp3 * 2);
    short* H2lo = (short*)alloc((size_t)N * Kp3 * 2);
    short* Wt1h = (short*)alloc((size_t)100 * Kp1 * 2);
    short* Wt1l = (short*)alloc((size_t)100 * Kp1 * 2);
    short* Wp1h = (short*)alloc((size_t)100 * Kp1 * 2);
    short* Wp1l = (short*)alloc((size_t)100 * Kp1 * 2);
    short* Wt2h = (short*)alloc((size_t)200 * Kp2 * 2);
    short* Wt2l = (short*)alloc((size_t)200 * Kp2 * 2);
    short* Wp2h = (short*)alloc((size_t)200 * Kp2 * 2);
    short* Wp2l = (short*)alloc((size_t)200 * Kp2 * 2);
    short* Wt3h = (short*)alloc((size_t)600 * Kp3 * 2);
    short* Wt3l = (short*)alloc((size_t)600 * Kp3 * 2);
    short* Wp3h = (short*)alloc((size_t)600 * Kp3 * 2);
    short* Wp3l = (short*)alloc((size_t)600 * Kp3 * 2);
    float* g = (float*)alloc((size_t)N * 4);
    float* Y = (float*)(ws + off);
    size_t ybudget = (ws_size > off) ? (ws_size - off) : 0;

    // Layer-3 channel chunk: Y chunk needs N*2*D*4 bytes; D multiple of 4.
    int Dc = (int)(ybudget / ((size_t)N * 8)) & ~3;
    if (Dc > 600) Dc = 600;
    if (Dc < 4) Dc = 4;

    // ---- pre-split weights & input ----
    {
        WSplitArgs a;
        const float* w[6] = {t1w, p1w, t2w, p2w, t3w, p3w};
        short* hi[6] = {Wt1h, Wp1h, Wt2h, Wp2h, Wt3h, Wp3h};
        short* lo[6] = {Wt1l, Wp1l, Wt2l, Wp2l, Wt3l, Wp3l};
        int rows[6] = {100, 100, 200, 200, 600, 600};
        int ci[6]   = {50, 50, 100, 100, 200, 200};
        int kp[6]   = {Kp1, Kp1, Kp2, Kp2, Kp3, Kp3};
        int total = 0;
        for (int i = 0; i < 6; ++i) {
            a.w[i] = w[i]; a.hi[i] = hi[i]; a.lo[i] = lo[i];
            a.rows[i] = rows[i]; a.ci[i] = ci[i]; a.kp[i] = kp[i];
            a.chunks[i] = rows[i] * (kp[i] >> 2);
            total += a.chunks[i];
        }
        a.total = total;
        split_w<<<(total + 255) / 256, 256, 0, stream>>>(a);
        split_x<<<2400, 256, 0, stream>>>(inputs, Xhi, Xlo);
    }

    // ---- EdgeConv 1: K=50(->64), Co=100 ----
    {
        dim3 grid(N / 128, 2);
        gemm_planes<<<grid, 256, 0, stream>>>(Xhi, Xlo, Kp1, Kp1 / BK,
                                              Wt1h, Wt1l, Wp1h, Wp1l, 100, Y);
        epi_flat<<<2400, 256, 0, stream>>>(Y, 100, Kp2, 5, nbr, t1b, p1b,
                                           H1hi, H1lo);
    }
    // ---- EdgeConv 2: K=100(->128), Co=200 ----
    {
        dim3 grid(N / 128, 4);
        gemm_planes<<<grid, 256, 0, stream>>>(H1hi, H1lo, Kp2, Kp2 / BK,
                                              Wt2h, Wt2l, Wp2h, Wp2l, 200, Y);
        epi_flat<<<4800, 256, 0, stream>>>(Y, 200, Kp3, 6, nbr, t2b, p2b,
                                           H2hi, H2lo);
    }
    // ---- EdgeConv 3: K=200(->256), Co=600, chunked over channels ----
    for (int d0 = 0; d0 < 600; d0 += Dc) {
        int D = (600 - d0 < Dc) ? (600 - d0) : Dc;
        dim3 grid(N / 128, (2 * D + 127) / 128);
        gemm_planes<<<grid, 256, 0, stream>>>(
            H2hi, H2lo, Kp3, Kp3 / BK,
            Wt3h + (size_t)d0 * Kp3, Wt3l + (size_t)d0 * Kp3,
            Wp3h + (size_t)d0 * Kp3, Wp3l + (size_t)d0 * Kp3, D, Y);
        epi3_wave<<<(N + 3) / 4, 256, 0, stream>>>(Y, D, nbr, t3b + d0,
                                                   p3b + d0, g, d0 == 0 ? 1 : 0);
    }
    // ---- FC head ----
    fc_head<<<64, 256, 0, stream>>>(g, fc1w, fc1b, fc2w, fc2b, fc3w, fc3b,
                                    fc4w, fc4b, fow, fob, out);
}